// Round 6
// baseline (241.306 us; speedup 1.0000x reference)
//
#include <hip/hip_runtime.h>

#define NN 20000
#define EE 320000
#define TE 340000        // EE + NN self loops
#define NEG 0.2f
#define NB_SCORE 1329    // ceil(TE/256)
#define NB_GEMM 625      // 20000 / 32
#define SCAN_CH 20       // ceil(20000/1024)

__device__ __forceinline__ float lrelu(float v) { return v > 0.f ? v : NEG * v; }

// ---------------- fp32 GEMM: h = x @ W, W staged through LDS (double-buffered) ----------------
// 256 threads (4 waves), 32 rows/block, 8 rows/thread, 4 cols (1 float4)/thread.
// LDS: x-tile 32KB + W double-buffer 2x16KB = 64KB -> 2 blocks/CU.
// Per 16-k chunk: cooperative W prefetch (4 float4/thread) hidden under 512 fma4.
__global__ __launch_bounds__(256, 2) void k_gemm(const float* __restrict__ x, const float* __restrict__ W,
                                                 const float* __restrict__ att, float* __restrict__ h,
                                                 float* __restrict__ as, float* __restrict__ ad,
                                                 float* __restrict__ bmaxT, int* __restrict__ cnt) {
    __shared__ float4 xt4[32][64];      // 32 rows x 256 k = 32 KB
    __shared__ float4 wt4[2][16][64];   // 2 x (16 k-rows x 256 cols) = 32 KB
    __shared__ float smax[4][8];
    const int tid = threadIdx.x;
    const int r0 = blockIdx.x * 32;
    const float4* x4 = (const float4*)x;
    const float4* W4 = (const float4*)W;

    if (tid < 32) cnt[r0 + tid] = 0;    // zero histogram (incremented in k_escale)

    #pragma unroll
    for (int i = 0; i < 8; ++i) {
        int slot = tid + i * 256;       // 2048 float4 slots
        xt4[slot >> 6][slot & 63] = x4[(r0 + (slot >> 6)) * 64 + (slot & 63)];
    }
    #pragma unroll
    for (int i = 0; i < 4; ++i) {
        int slot = tid + i * 256;       // 1024 slots = 16 k-rows x 64 col4
        wt4[0][slot >> 6][slot & 63] = W4[(slot >> 6) * 64 + (slot & 63)];
    }
    __syncthreads();

    const int tx = tid & 63, ty = tid >> 6;
    const int head = tx >> 4, sub = tx & 15;
    float4 acc[8];
    #pragma unroll
    for (int r = 0; r < 8; ++r) acc[r] = make_float4(0.f, 0.f, 0.f, 0.f);

    int p = 0;
    for (int c = 0; c < 16; ++c) {
        // cooperative prefetch of next 16-k W chunk into the other buffer
        if (c < 15) {
            #pragma unroll
            for (int i = 0; i < 4; ++i) {
                int slot = tid + i * 256;
                wt4[p ^ 1][slot >> 6][slot & 63] = W4[((c + 1) * 16 + (slot >> 6)) * 64 + (slot & 63)];
            }
        }
        #pragma unroll
        for (int k4l = 0; k4l < 4; ++k4l) {
            float4 wv[4];
            #pragma unroll
            for (int j = 0; j < 4; ++j) wv[j] = wt4[p][k4l * 4 + j][tx];
            #pragma unroll
            for (int r = 0; r < 8; ++r) {
                float4 xv = xt4[ty * 8 + r][c * 4 + k4l];   // wave-uniform -> LDS broadcast
                acc[r].x += xv.x * wv[0].x + xv.y * wv[1].x + xv.z * wv[2].x + xv.w * wv[3].x;
                acc[r].y += xv.x * wv[0].y + xv.y * wv[1].y + xv.z * wv[2].y + xv.w * wv[3].y;
                acc[r].z += xv.x * wv[0].z + xv.y * wv[1].z + xv.z * wv[2].z + xv.w * wv[3].z;
                acc[r].w += xv.x * wv[0].w + xv.y * wv[1].w + xv.z * wv[2].w + xv.w * wv[3].w;
            }
        }
        __syncthreads();
        p ^= 1;
    }

    // epilogue: h store + alpha_src/dst (16-lane reduce) + per-wave alpha max
    float4 av = ((const float4*)att)[head * 32 + sub];        // a_src coefs
    float4 dv = ((const float4*)att)[head * 32 + 16 + sub];   // a_dst coefs
    float mxs = -1e30f, mxd = -1e30f;
    float4* h4 = (float4*)h;
    #pragma unroll
    for (int r = 0; r < 8; ++r) {
        int g = r0 + ty * 8 + r;
        h4[g * 64 + tx] = acc[r];
        float l0 = lrelu(acc[r].x), l1 = lrelu(acc[r].y), l2 = lrelu(acc[r].z), l3 = lrelu(acc[r].w);
        float ss = l0 * av.x + l1 * av.y + l2 * av.z + l3 * av.w;
        float sd = l0 * dv.x + l1 * dv.y + l2 * dv.z + l3 * dv.w;
        #pragma unroll
        for (int m = 1; m < 16; m <<= 1) {
            ss += __shfl_xor(ss, m, 64);
            sd += __shfl_xor(sd, m, 64);
        }
        if (sub == 0) {
            as[g * 4 + head] = ss;
            ad[g * 4 + head] = sd;
            mxs = fmaxf(mxs, ss);
            mxd = fmaxf(mxd, sd);
        }
    }
    if (sub == 0) { smax[ty][head] = mxs; smax[ty][4 + head] = mxd; }
    __syncthreads();
    if (tid < 8) {
        float m = fmaxf(fmaxf(smax[0][tid], smax[1][tid]), fmaxf(smax[2][tid], smax[3][tid]));
        bmaxT[tid * 1280 + blockIdx.x] = m;   // transposed for coalesced reduce
    }
}

// ---------------- Es/Ed = exp(a - M) in place + dst histogram ----------------
__global__ __launch_bounds__(256) void k_escale(const float* __restrict__ bmaxT,
                                                float* __restrict__ as, float* __restrict__ ad,
                                                const int* __restrict__ ed, int* __restrict__ cnt) {
    __shared__ float M[8];
    int tid = threadIdx.x;
    int g = tid >> 5, l = tid & 31;     // 8 groups of 32 lanes reduce 8 maxes
    float m = -1e30f;
    for (int i = l; i < NB_GEMM; i += 32) m = fmaxf(m, bmaxT[g * 1280 + i]);
    #pragma unroll
    for (int s = 16; s > 0; s >>= 1) m = fmaxf(m, __shfl_xor(m, s, 32));
    if (l == 0) M[g] = m;
    __syncthreads();
    int n = blockIdx.x * 256 + tid;
    if (n < NN) {
        float4 a = ((float4*)as)[n];
        a.x = expf(a.x - M[0]); a.y = expf(a.y - M[1]);
        a.z = expf(a.z - M[2]); a.w = expf(a.w - M[3]);
        ((float4*)as)[n] = a;
        float4 d = ((float4*)ad)[n];
        d.x = expf(d.x - M[4]); d.y = expf(d.y - M[5]);
        d.z = expf(d.z - M[6]); d.w = expf(d.w - M[7]);
        ((float4*)ad)[n] = d;
    }
    // dst histogram (cnt zeroed by k_gemm)
    int stride = gridDim.x * 256;
    for (int e = blockIdx.x * 256 + tid; e < TE; e += stride) {
        int di = e < EE ? ed[e] : e - EE;
        atomicAdd(cnt + di, 1);
    }
}

// ---------------- single-block exclusive scan of cnt -> offs, cursor ----------------
__global__ __launch_bounds__(1024) void k_scan(const int* __restrict__ cnt, int* __restrict__ offs,
                                               int* __restrict__ cursor) {
    __shared__ int wsum[16];
    int tid = threadIdx.x, lane = tid & 63, wid = tid >> 6;
    int base = tid * SCAN_CH;
    int loc[SCAN_CH];
    int sum = 0;
    #pragma unroll
    for (int i = 0; i < SCAN_CH; ++i) {
        int idx = base + i;
        int v = (idx < NN) ? cnt[idx] : 0;
        loc[i] = sum;
        sum += v;
    }
    int v = sum;
    #pragma unroll
    for (int off = 1; off < 64; off <<= 1) {
        int t = __shfl_up(v, off, 64);
        if (lane >= off) v += t;
    }
    if (lane == 63) wsum[wid] = v;
    __syncthreads();
    if (tid < 16) {
        int w = wsum[tid];
        #pragma unroll
        for (int off = 1; off < 16; off <<= 1) {
            int t = __shfl_up(w, off, 16);
            if (tid >= off) w += t;
        }
        wsum[tid] = w;
    }
    __syncthreads();
    int waveoff = (wid == 0) ? 0 : wsum[wid - 1];
    int excl = waveoff + v - sum;
    #pragma unroll
    for (int i = 0; i < SCAN_CH; ++i) {
        int idx = base + i;
        if (idx < NN) { int o = excl + loc[i]; offs[idx] = o; cursor[idx] = o; }
    }
    if (tid == 1023) offs[NN] = waveoff + v;   // == TE
}

// ---------------- bucket fill: src per dst bin + block psum (p = Es*Ed) ----------------
__global__ __launch_bounds__(256) void k_fill(const int* __restrict__ es, const int* __restrict__ ed,
                                              const float* __restrict__ Es, const float* __restrict__ Ed,
                                              int* __restrict__ cursor, int* __restrict__ bsi,
                                              float4* __restrict__ psum) {
    __shared__ float4 ls[4];
    int e = blockIdx.x * 256 + threadIdx.x;
    int tid = threadIdx.x, lane = tid & 63, wid = tid >> 6;
    float4 p = {0.f, 0.f, 0.f, 0.f};
    if (e < TE) {
        int si = e < EE ? es[e] : e - EE;
        int di = e < EE ? ed[e] : e - EE;
        float4 a = ((const float4*)Es)[si];
        float4 d = ((const float4*)Ed)[di];
        p.x = a.x * d.x; p.y = a.y * d.y; p.z = a.z * d.z; p.w = a.w * d.w;
        int pos = atomicAdd(cursor + di, 1);
        bsi[pos] = si;
    }
    #pragma unroll
    for (int m = 32; m > 0; m >>= 1) {
        p.x += __shfl_xor(p.x, m, 64);
        p.y += __shfl_xor(p.y, m, 64);
        p.z += __shfl_xor(p.z, m, 64);
        p.w += __shfl_xor(p.w, m, 64);
    }
    if (lane == 0) ls[wid] = p;
    __syncthreads();
    if (tid == 0) {
        float4 t;
        t.x = ls[0].x + ls[1].x + ls[2].x + ls[3].x;
        t.y = ls[0].y + ls[1].y + ls[2].y + ls[3].y;
        t.z = ls[0].z + ls[1].z + ls[2].z + ls[3].z;
        t.w = ls[0].w + ls[1].w + ls[2].w + ls[3].w;
        psum[blockIdx.x] = t;
    }
}

// ---------------- combine psum -> invZ ----------------
__global__ __launch_bounds__(256) void k_comb(const float4* __restrict__ psum, float* __restrict__ hstat) {
    __shared__ float4 zred[4];
    int tid = threadIdx.x, lane = tid & 63, wid = tid >> 6;
    float4 z = {0.f, 0.f, 0.f, 0.f};
    for (int i = tid; i < NB_SCORE; i += 256) {
        float4 s = psum[i];
        z.x += s.x; z.y += s.y; z.z += s.z; z.w += s.w;
    }
    #pragma unroll
    for (int m = 32; m > 0; m >>= 1) {
        z.x += __shfl_xor(z.x, m, 64);
        z.y += __shfl_xor(z.y, m, 64);
        z.z += __shfl_xor(z.z, m, 64);
        z.w += __shfl_xor(z.w, m, 64);
    }
    if (lane == 0) zred[wid] = z;
    __syncthreads();
    if (tid == 0) {
        float4 t;
        t.x = zred[0].x + zred[1].x + zred[2].x + zred[3].x;
        t.y = zred[0].y + zred[1].y + zred[2].y + zred[3].y;
        t.z = zred[0].z + zred[1].z + zred[2].z + zred[3].z;
        t.w = zred[0].w + zred[1].w + zred[2].w + zred[3].w;
        hstat[0] = 1.0f / t.x; hstat[1] = 1.0f / t.y;
        hstat[2] = 1.0f / t.z; hstat[3] = 1.0f / t.w;
    }
}

// ---------------- gather: out[n] = b + invZ*Ed[n] * sum_{e in bin(n)} Es[src_e] * h[src_e] ----------------
// one wave per dst node; Ed[n], invZ are wave-uniform; inner loop = bsi + Es scalar + h row
__global__ __launch_bounds__(256) void k_gather(const int* __restrict__ offs, const int* __restrict__ bsi,
                                                const float* __restrict__ Es, const float* __restrict__ Ed,
                                                const float* __restrict__ h, const float* __restrict__ b,
                                                const float* __restrict__ hstat, float* __restrict__ out) {
    int n = blockIdx.x * 4 + (threadIdx.x >> 6);
    int lane = threadIdx.x & 63;
    int head = lane >> 4;
    int beg = offs[n], end = offs[n + 1];
    const float4* h4 = (const float4*)h;
    float4 a0 = {0.f, 0.f, 0.f, 0.f}, a1 = a0, a2 = a0, a3 = a0;
    int j = beg;
    for (; j + 7 < end; j += 8) {
        int s0 = bsi[j],     s1 = bsi[j + 1], s2 = bsi[j + 2], s3 = bsi[j + 3];
        int s4 = bsi[j + 4], s5 = bsi[j + 5], s6 = bsi[j + 6], s7 = bsi[j + 7];
        float w0 = Es[s0 * 4 + head], w1 = Es[s1 * 4 + head];
        float w2 = Es[s2 * 4 + head], w3 = Es[s3 * 4 + head];
        float w4 = Es[s4 * 4 + head], w5 = Es[s5 * 4 + head];
        float w6 = Es[s6 * 4 + head], w7 = Es[s7 * 4 + head];
        float4 v0 = h4[s0 * 64 + lane], v1 = h4[s1 * 64 + lane];
        float4 v2 = h4[s2 * 64 + lane], v3 = h4[s3 * 64 + lane];
        float4 v4 = h4[s4 * 64 + lane], v5 = h4[s5 * 64 + lane];
        float4 v6 = h4[s6 * 64 + lane], v7 = h4[s7 * 64 + lane];
        a0.x += w0 * v0.x; a0.y += w0 * v0.y; a0.z += w0 * v0.z; a0.w += w0 * v0.w;
        a1.x += w1 * v1.x; a1.y += w1 * v1.y; a1.z += w1 * v1.z; a1.w += w1 * v1.w;
        a2.x += w2 * v2.x; a2.y += w2 * v2.y; a2.z += w2 * v2.z; a2.w += w2 * v2.w;
        a3.x += w3 * v3.x; a3.y += w3 * v3.y; a3.z += w3 * v3.z; a3.w += w3 * v3.w;
        a0.x += w4 * v4.x; a0.y += w4 * v4.y; a0.z += w4 * v4.z; a0.w += w4 * v4.w;
        a1.x += w5 * v5.x; a1.y += w5 * v5.y; a1.z += w5 * v5.z; a1.w += w5 * v5.w;
        a2.x += w6 * v6.x; a2.y += w6 * v6.y; a2.z += w6 * v6.z; a2.w += w6 * v6.w;
        a3.x += w7 * v7.x; a3.y += w7 * v7.y; a3.z += w7 * v7.z; a3.w += w7 * v7.w;
    }
    for (; j + 3 < end; j += 4) {
        int s0 = bsi[j], s1 = bsi[j + 1], s2 = bsi[j + 2], s3 = bsi[j + 3];
        float w0 = Es[s0 * 4 + head], w1 = Es[s1 * 4 + head];
        float w2 = Es[s2 * 4 + head], w3 = Es[s3 * 4 + head];
        float4 v0 = h4[s0 * 64 + lane], v1 = h4[s1 * 64 + lane];
        float4 v2 = h4[s2 * 64 + lane], v3 = h4[s3 * 64 + lane];
        a0.x += w0 * v0.x; a0.y += w0 * v0.y; a0.z += w0 * v0.z; a0.w += w0 * v0.w;
        a1.x += w1 * v1.x; a1.y += w1 * v1.y; a1.z += w1 * v1.z; a1.w += w1 * v1.w;
        a2.x += w2 * v2.x; a2.y += w2 * v2.y; a2.z += w2 * v2.z; a2.w += w2 * v2.w;
        a3.x += w3 * v3.x; a3.y += w3 * v3.y; a3.z += w3 * v3.z; a3.w += w3 * v3.w;
    }
    for (; j < end; ++j) {
        int s = bsi[j];
        float w = Es[s * 4 + head];
        float4 hv = h4[s * 64 + lane];
        a0.x += w * hv.x; a0.y += w * hv.y; a0.z += w * hv.z; a0.w += w * hv.w;
    }
    float scale = hstat[head] * Ed[n * 4 + head];   // invZ * Ed_n (uniform per 16-lane group)
    float4 bb = ((const float4*)b)[lane];
    float4 o;
    o.x = bb.x + scale * (a0.x + a1.x + a2.x + a3.x);
    o.y = bb.y + scale * (a0.y + a1.y + a2.y + a3.y);
    o.z = bb.z + scale * (a0.z + a1.z + a2.z + a3.z);
    o.w = bb.w + scale * (a0.w + a1.w + a2.w + a3.w);
    ((float4*)out)[n * 64 + lane] = o;
}

extern "C" void kernel_launch(void* const* d_in, const int* in_sizes, int n_in,
                              void* d_out, int out_size, void* d_ws, size_t ws_size,
                              hipStream_t stream) {
    const float* x   = (const float*)d_in[0];
    const float* W   = (const float*)d_in[1];
    const float* att = (const float*)d_in[2];
    const float* b   = (const float*)d_in[3];
    const int*  eidx = (const int*)d_in[4];
    const int* es = eidx;        // edge_index[0] : sources
    const int* ed = eidx + EE;   // edge_index[1] : destinations
    float* out = (float*)d_out;

    float* ws = (float*)d_ws;
    float* h      = ws;                        // 5,120,000 f
    float* as     = h + NN * 256;              // 80,000 f (becomes Es in place)
    float* ad     = as + NN * 4;               // 80,000 f (becomes Ed in place)
    int*   cnt    = (int*)(ad + NN * 4);       // 20,000 i
    int*   offs   = cnt + NN;                  // 20,008 i (sentinel + pad)
    int*   cursor = offs + NN + 8;             // 20,000 i
    int*   bsi    = cursor + NN;               // 340,000 i
    float* bmaxT  = (float*)(bsi + TE);        // 8 x 1280 f
    float4* psum  = (float4*)(bmaxT + 8 * 1280); // NB_SCORE f4
    float* hstat  = (float*)(psum + NB_SCORE + 3); // 4 f (invZ)

    k_gemm  <<<NB_GEMM, 256, 0, stream>>>(x, W, att, h, as, ad, bmaxT, cnt);
    k_escale<<<320, 256, 0, stream>>>(bmaxT, as, ad, ed, cnt);
    k_scan  <<<1, 1024, 0, stream>>>(cnt, offs, cursor);
    k_fill  <<<NB_SCORE, 256, 0, stream>>>(es, ed, as, ad, cursor, bsi, psum);
    k_comb  <<<1, 256, 0, stream>>>(psum, hstat);
    k_gather<<<NN / 4, 256, 0, stream>>>(offs, bsi, as, ad, h, b, hstat, out);
}

// Round 7
// 168.087 us; speedup vs baseline: 1.4356x; 1.4356x over previous
//
#include <hip/hip_runtime.h>

#define NN 20000
#define EE 320000
#define TE 340000        // EE + NN self loops
#define NEG 0.2f
#define NB_SCORE 1329    // ceil(TE/256)
#define NB_GEMM 625      // 20000 / 32
#define NB_ESC 320       // escale grid
#define SCAN_CH 20       // ceil(20000/1024)

__device__ __forceinline__ float lrelu(float v) { return v > 0.f ? v : NEG * v; }

// ---------------- fp32 GEMM: h = x @ W (+ alpha epilogue + per-block alpha max + cnt zero) ----------------
// 256 threads (4 waves), 32 rows/block, 8 rows/thread. W direct from L2, register double-buffered.
// W L2 traffic: 625 blocks x 4 waves x 256KB = 640MB (~19us floor); VALU floor 16.7us.
__global__ __launch_bounds__(256, 2) void k_gemm(const float* __restrict__ x, const float* __restrict__ W,
                                                 const float* __restrict__ att, float* __restrict__ h,
                                                 float* __restrict__ as, float* __restrict__ ad,
                                                 float* __restrict__ bmaxT, int* __restrict__ cnt) {
    __shared__ float4 xt4[32][64];   // 32 rows x 256 k = 32 KB
    __shared__ float smax[4][8];
    const int tid = threadIdx.x;
    const int r0 = blockIdx.x * 32;
    const float4* x4 = (const float4*)x;
    const float4* W4 = (const float4*)W;

    if (tid < 32) cnt[r0 + tid] = 0;   // zero histogram (incremented later, in k_escale)

    #pragma unroll
    for (int i = 0; i < 8; ++i) {
        int slot = tid + i * 256;      // 2048 float4 slots
        xt4[slot >> 6][slot & 63] = x4[(r0 + (slot >> 6)) * 64 + (slot & 63)];
    }
    __syncthreads();

    const int tx = tid & 63, ty = tid >> 6;
    const int head = tx >> 4, sub = tx & 15;
    float4 acc[8];
    #pragma unroll
    for (int r = 0; r < 8; ++r) acc[r] = make_float4(0.f, 0.f, 0.f, 0.f);

    auto fma4 = [&](const float4* wv, int k4) {
        #pragma unroll
        for (int r = 0; r < 8; ++r) {
            float4 xv = xt4[ty * 8 + r][k4];   // wave-uniform -> LDS broadcast
            acc[r].x += xv.x * wv[0].x + xv.y * wv[1].x + xv.z * wv[2].x + xv.w * wv[3].x;
            acc[r].y += xv.x * wv[0].y + xv.y * wv[1].y + xv.z * wv[2].y + xv.w * wv[3].y;
            acc[r].z += xv.x * wv[0].z + xv.y * wv[1].z + xv.z * wv[2].z + xv.w * wv[3].z;
            acc[r].w += xv.x * wv[0].w + xv.y * wv[1].w + xv.z * wv[2].w + xv.w * wv[3].w;
        }
    };

    float4 wv[4], wn[4];
    #pragma unroll
    for (int j = 0; j < 4; ++j) wv[j] = W4[j * 64 + tx];
    #pragma unroll 2
    for (int k4 = 0; k4 < 63; ++k4) {
        #pragma unroll
        for (int j = 0; j < 4; ++j) wn[j] = W4[((k4 + 1) * 4 + j) * 64 + tx];
        fma4(wv, k4);
        #pragma unroll
        for (int j = 0; j < 4; ++j) wv[j] = wn[j];
    }
    fma4(wv, 63);

    // epilogue: h store + alpha_src/dst (16-lane reduce) + per-wave alpha max
    float4 av = ((const float4*)att)[head * 32 + sub];        // a_src coefs
    float4 dv = ((const float4*)att)[head * 32 + 16 + sub];   // a_dst coefs
    float mxs = -1e30f, mxd = -1e30f;
    float4* h4 = (float4*)h;
    #pragma unroll
    for (int r = 0; r < 8; ++r) {
        int g = r0 + ty * 8 + r;
        h4[g * 64 + tx] = acc[r];
        float l0 = lrelu(acc[r].x), l1 = lrelu(acc[r].y), l2 = lrelu(acc[r].z), l3 = lrelu(acc[r].w);
        float ss = l0 * av.x + l1 * av.y + l2 * av.z + l3 * av.w;
        float sd = l0 * dv.x + l1 * dv.y + l2 * dv.z + l3 * dv.w;
        #pragma unroll
        for (int m = 1; m < 16; m <<= 1) {
            ss += __shfl_xor(ss, m, 64);
            sd += __shfl_xor(sd, m, 64);
        }
        if (sub == 0) {
            as[g * 4 + head] = ss;
            ad[g * 4 + head] = sd;
            mxs = fmaxf(mxs, ss);
            mxd = fmaxf(mxd, sd);
        }
    }
    if (sub == 0) { smax[ty][head] = mxs; smax[ty][4 + head] = mxd; }
    __syncthreads();
    if (tid < 8) {
        float m = fmaxf(fmaxf(smax[0][tid], smax[1][tid]), fmaxf(smax[2][tid], smax[3][tid]));
        bmaxT[tid * 1280 + blockIdx.x] = m;   // transposed for coalesced reduce
    }
}

// ---------------- Es/Ed = exp(a - M) (separate arrays) + dst histogram + Z partial sums ----------------
__global__ __launch_bounds__(256) void k_escale(const float* __restrict__ bmaxT,
                                                const float* __restrict__ as, const float* __restrict__ ad,
                                                float* __restrict__ Es, float* __restrict__ Ed,
                                                const int* __restrict__ es, const int* __restrict__ ed,
                                                int* __restrict__ cnt, float4* __restrict__ psum) {
    __shared__ float M[8];
    __shared__ float4 ls[4];
    int tid = threadIdx.x, lane = tid & 63, wid = tid >> 6;
    int g = tid >> 5, l = tid & 31;     // 8 groups of 32 lanes reduce 8 maxes
    float m = -1e30f;
    for (int i = l; i < NB_GEMM; i += 32) m = fmaxf(m, bmaxT[g * 1280 + i]);
    #pragma unroll
    for (int s = 16; s > 0; s >>= 1) m = fmaxf(m, __shfl_xor(m, s, 32));
    if (l == 0) M[g] = m;
    __syncthreads();
    float Ms0 = M[0], Ms1 = M[1], Ms2 = M[2], Ms3 = M[3];
    float Md0 = M[4], Md1 = M[5], Md2 = M[6], Md3 = M[7];
    float c0 = Ms0 + Md0, c1 = Ms1 + Md1, c2 = Ms2 + Md2, c3 = Ms3 + Md3;

    int stride = NB_ESC * 256;
    // nodes: exp tables (raw as/ad untouched -> no cross-block race)
    for (int n = blockIdx.x * 256 + tid; n < NN; n += stride) {
        float4 a = ((const float4*)as)[n];
        float4 ea = {expf(a.x - Ms0), expf(a.y - Ms1), expf(a.z - Ms2), expf(a.w - Ms3)};
        ((float4*)Es)[n] = ea;
        float4 d = ((const float4*)ad)[n];
        float4 edv = {expf(d.x - Md0), expf(d.y - Md1), expf(d.z - Md2), expf(d.w - Md3)};
        ((float4*)Ed)[n] = edv;
    }
    // edges: dst histogram + Z partials from raw scores
    float4 z = {0.f, 0.f, 0.f, 0.f};
    for (int e = blockIdx.x * 256 + tid; e < TE; e += stride) {
        int si = e < EE ? es[e] : e - EE;
        int di = e < EE ? ed[e] : e - EE;
        atomicAdd(cnt + di, 1);
        float4 a = ((const float4*)as)[si];
        float4 d = ((const float4*)ad)[di];
        z.x += expf(a.x + d.x - c0);
        z.y += expf(a.y + d.y - c1);
        z.z += expf(a.z + d.z - c2);
        z.w += expf(a.w + d.w - c3);
    }
    #pragma unroll
    for (int s = 32; s > 0; s >>= 1) {
        z.x += __shfl_xor(z.x, s, 64);
        z.y += __shfl_xor(z.y, s, 64);
        z.z += __shfl_xor(z.z, s, 64);
        z.w += __shfl_xor(z.w, s, 64);
    }
    if (lane == 0) ls[wid] = z;
    __syncthreads();
    if (tid == 0) {
        float4 t;
        t.x = ls[0].x + ls[1].x + ls[2].x + ls[3].x;
        t.y = ls[0].y + ls[1].y + ls[2].y + ls[3].y;
        t.z = ls[0].z + ls[1].z + ls[2].z + ls[3].z;
        t.w = ls[0].w + ls[1].w + ls[2].w + ls[3].w;
        psum[blockIdx.x] = t;
    }
}

// ---------------- single-block: exclusive scan of cnt -> offs/cursor, + Z combine -> invZ ----------------
__global__ __launch_bounds__(1024) void k_scan(const int* __restrict__ cnt, int* __restrict__ offs,
                                               int* __restrict__ cursor, const float4* __restrict__ psum,
                                               float* __restrict__ hstat) {
    __shared__ int wsum[16];
    __shared__ float4 zred[16];
    int tid = threadIdx.x, lane = tid & 63, wid = tid >> 6;
    int base = tid * SCAN_CH;
    int loc[SCAN_CH];
    int sum = 0;
    #pragma unroll
    for (int i = 0; i < SCAN_CH; ++i) {
        int idx = base + i;
        int v = (idx < NN) ? cnt[idx] : 0;
        loc[i] = sum;
        sum += v;
    }
    int v = sum;
    #pragma unroll
    for (int off = 1; off < 64; off <<= 1) {
        int t = __shfl_up(v, off, 64);
        if (lane >= off) v += t;
    }
    if (lane == 63) wsum[wid] = v;
    __syncthreads();
    if (tid < 16) {
        int w = wsum[tid];
        #pragma unroll
        for (int off = 1; off < 16; off <<= 1) {
            int t = __shfl_up(w, off, 16);
            if (tid >= off) w += t;
        }
        wsum[tid] = w;
    }
    __syncthreads();
    int waveoff = (wid == 0) ? 0 : wsum[wid - 1];
    int excl = waveoff + v - sum;
    #pragma unroll
    for (int i = 0; i < SCAN_CH; ++i) {
        int idx = base + i;
        if (idx < NN) { int o = excl + loc[i]; offs[idx] = o; cursor[idx] = o; }
    }
    if (tid == 1023) offs[NN] = waveoff + v;   // == TE

    // ---- Z combine (psum from k_escale's NB_ESC blocks) ----
    float4 z = {0.f, 0.f, 0.f, 0.f};
    for (int i = tid; i < NB_ESC; i += 1024) {
        float4 s = psum[i];
        z.x += s.x; z.y += s.y; z.z += s.z; z.w += s.w;
    }
    #pragma unroll
    for (int m = 32; m > 0; m >>= 1) {
        z.x += __shfl_xor(z.x, m, 64);
        z.y += __shfl_xor(z.y, m, 64);
        z.z += __shfl_xor(z.z, m, 64);
        z.w += __shfl_xor(z.w, m, 64);
    }
    if (lane == 0) zred[wid] = z;
    __syncthreads();
    if (tid == 0) {
        float4 t = {0.f, 0.f, 0.f, 0.f};
        #pragma unroll
        for (int i = 0; i < 16; ++i) {
            t.x += zred[i].x; t.y += zred[i].y; t.z += zred[i].z; t.w += zred[i].w;
        }
        hstat[0] = 1.0f / t.x; hstat[1] = 1.0f / t.y;
        hstat[2] = 1.0f / t.z; hstat[3] = 1.0f / t.w;
    }
}

// ---------------- bucket fill: pure src scatter per dst bin ----------------
__global__ __launch_bounds__(256) void k_fill(const int* __restrict__ es, const int* __restrict__ ed,
                                              int* __restrict__ cursor, int* __restrict__ bsi) {
    int e = blockIdx.x * 256 + threadIdx.x;
    if (e >= TE) return;
    int si = e < EE ? es[e] : e - EE;
    int di = e < EE ? ed[e] : e - EE;
    int pos = atomicAdd(cursor + di, 1);
    bsi[pos] = si;
}

// ---------------- gather: out[n] = b + invZ*Ed[n] * sum_{e in bin(n)} Es[src_e] * h[src_e] ----------------
// one wave per dst node; Ed[n], invZ wave-uniform; x8 unroll for MLP
__global__ __launch_bounds__(256) void k_gather(const int* __restrict__ offs, const int* __restrict__ bsi,
                                                const float* __restrict__ Es, const float* __restrict__ Ed,
                                                const float* __restrict__ h, const float* __restrict__ b,
                                                const float* __restrict__ hstat, float* __restrict__ out) {
    int n = blockIdx.x * 4 + (threadIdx.x >> 6);
    int lane = threadIdx.x & 63;
    int head = lane >> 4;
    int beg = offs[n], end = offs[n + 1];
    const float4* h4 = (const float4*)h;
    float4 a0 = {0.f, 0.f, 0.f, 0.f}, a1 = a0, a2 = a0, a3 = a0;
    int j = beg;
    for (; j + 7 < end; j += 8) {
        int s0 = bsi[j],     s1 = bsi[j + 1], s2 = bsi[j + 2], s3 = bsi[j + 3];
        int s4 = bsi[j + 4], s5 = bsi[j + 5], s6 = bsi[j + 6], s7 = bsi[j + 7];
        float w0 = Es[s0 * 4 + head], w1 = Es[s1 * 4 + head];
        float w2 = Es[s2 * 4 + head], w3 = Es[s3 * 4 + head];
        float w4 = Es[s4 * 4 + head], w5 = Es[s5 * 4 + head];
        float w6 = Es[s6 * 4 + head], w7 = Es[s7 * 4 + head];
        float4 v0 = h4[s0 * 64 + lane], v1 = h4[s1 * 64 + lane];
        float4 v2 = h4[s2 * 64 + lane], v3 = h4[s3 * 64 + lane];
        float4 v4 = h4[s4 * 64 + lane], v5 = h4[s5 * 64 + lane];
        float4 v6 = h4[s6 * 64 + lane], v7 = h4[s7 * 64 + lane];
        a0.x += w0 * v0.x; a0.y += w0 * v0.y; a0.z += w0 * v0.z; a0.w += w0 * v0.w;
        a1.x += w1 * v1.x; a1.y += w1 * v1.y; a1.z += w1 * v1.z; a1.w += w1 * v1.w;
        a2.x += w2 * v2.x; a2.y += w2 * v2.y; a2.z += w2 * v2.z; a2.w += w2 * v2.w;
        a3.x += w3 * v3.x; a3.y += w3 * v3.y; a3.z += w3 * v3.z; a3.w += w3 * v3.w;
        a0.x += w4 * v4.x; a0.y += w4 * v4.y; a0.z += w4 * v4.z; a0.w += w4 * v4.w;
        a1.x += w5 * v5.x; a1.y += w5 * v5.y; a1.z += w5 * v5.z; a1.w += w5 * v5.w;
        a2.x += w6 * v6.x; a2.y += w6 * v6.y; a2.z += w6 * v6.z; a2.w += w6 * v6.w;
        a3.x += w7 * v7.x; a3.y += w7 * v7.y; a3.z += w7 * v7.z; a3.w += w7 * v7.w;
    }
    for (; j + 3 < end; j += 4) {
        int s0 = bsi[j], s1 = bsi[j + 1], s2 = bsi[j + 2], s3 = bsi[j + 3];
        float w0 = Es[s0 * 4 + head], w1 = Es[s1 * 4 + head];
        float w2 = Es[s2 * 4 + head], w3 = Es[s3 * 4 + head];
        float4 v0 = h4[s0 * 64 + lane], v1 = h4[s1 * 64 + lane];
        float4 v2 = h4[s2 * 64 + lane], v3 = h4[s3 * 64 + lane];
        a0.x += w0 * v0.x; a0.y += w0 * v0.y; a0.z += w0 * v0.z; a0.w += w0 * v0.w;
        a1.x += w1 * v1.x; a1.y += w1 * v1.y; a1.z += w1 * v1.z; a1.w += w1 * v1.w;
        a2.x += w2 * v2.x; a2.y += w2 * v2.y; a2.z += w2 * v2.z; a2.w += w2 * v2.w;
        a3.x += w3 * v3.x; a3.y += w3 * v3.y; a3.z += w3 * v3.z; a3.w += w3 * v3.w;
    }
    for (; j < end; ++j) {
        int s = bsi[j];
        float w = Es[s * 4 + head];
        float4 hv = h4[s * 64 + lane];
        a0.x += w * hv.x; a0.y += w * hv.y; a0.z += w * hv.z; a0.w += w * hv.w;
    }
    float scale = hstat[head] * Ed[n * 4 + head];   // invZ * Ed_n (uniform per 16-lane group)
    float4 bb = ((const float4*)b)[lane];
    float4 o;
    o.x = bb.x + scale * (a0.x + a1.x + a2.x + a3.x);
    o.y = bb.y + scale * (a0.y + a1.y + a2.y + a3.y);
    o.z = bb.z + scale * (a0.z + a1.z + a2.z + a3.z);
    o.w = bb.w + scale * (a0.w + a1.w + a2.w + a3.w);
    ((float4*)out)[n * 64 + lane] = o;
}

extern "C" void kernel_launch(void* const* d_in, const int* in_sizes, int n_in,
                              void* d_out, int out_size, void* d_ws, size_t ws_size,
                              hipStream_t stream) {
    const float* x   = (const float*)d_in[0];
    const float* W   = (const float*)d_in[1];
    const float* att = (const float*)d_in[2];
    const float* b   = (const float*)d_in[3];
    const int*  eidx = (const int*)d_in[4];
    const int* es = eidx;        // edge_index[0] : sources
    const int* ed = eidx + EE;   // edge_index[1] : destinations
    float* out = (float*)d_out;

    float* ws = (float*)d_ws;
    float* h      = ws;                        // 5,120,000 f
    float* as     = h + NN * 256;              // 80,000 f (raw scores)
    float* ad     = as + NN * 4;               // 80,000 f
    float* Es     = ad + NN * 4;               // 80,000 f (exp tables)
    float* Ed     = Es + NN * 4;               // 80,000 f
    int*   cnt    = (int*)(Ed + NN * 4);       // 20,000 i
    int*   offs   = cnt + NN;                  // 20,008 i (sentinel + pad)
    int*   cursor = offs + NN + 8;             // 20,000 i
    int*   bsi    = cursor + NN;               // 340,000 i
    float* bmaxT  = (float*)(bsi + TE);        // 8 x 1280 f
    float4* psum  = (float4*)(bmaxT + 8 * 1280); // NB_ESC f4
    float* hstat  = (float*)(psum + NB_ESC);   // 4 f (invZ)

    k_gemm  <<<NB_GEMM, 256, 0, stream>>>(x, W, att, h, as, ad, bmaxT, cnt);
    k_escale<<<NB_ESC, 256, 0, stream>>>(bmaxT, as, ad, Es, Ed, es, ed, cnt, psum);
    k_scan  <<<1, 1024, 0, stream>>>(cnt, offs, cursor, psum, hstat);
    k_fill  <<<NB_SCORE, 256, 0, stream>>>(es, ed, cursor, bsi);
    k_gather<<<NN / 4, 256, 0, stream>>>(offs, bsi, Es, Ed, h, b, hstat, out);
}